// Round 5
// baseline (429.147 us; speedup 1.0000x reference)
//
#include <hip/hip_runtime.h>
#include <math.h>

typedef float f32x16 __attribute__((ext_vector_type(16)));
typedef short s16x8 __attribute__((ext_vector_type(8)));

namespace {
constexpr int B_ = 4, H_ = 16, T_ = 2048, K_ = 128, V_ = 128;
constexpr int BHn = B_ * H_;
constexpr int C = 32;            // chunk length
constexpr int NCH = T_ / C;      // 64 chunks
constexpr int NS = 8;            // V slices
constexpr int VS = V_ / NS;      // 16 columns per block
constexpr float SCALE = 0.08838834764831845f; // 128^-0.5
constexpr int SK = 136;          // bf16 row stride for [*][K] arrays
constexpr int SR = 40;           // bf16 row stride for [*][C] arrays
constexpr int SF = 36;           // f32 row stride for [C][C] arrays
}

__device__ __forceinline__ ushort f2bf(float x) {
  unsigned u = __builtin_bit_cast(unsigned, x);
  u += 0x7FFF + ((u >> 16) & 1);       // RNE
  return (ushort)(u >> 16);
}

// barrier that waits only on LDS ops: prefetch global loads / O-stores stay in flight
__device__ __forceinline__ void bar_lds() {
  asm volatile("s_waitcnt lgkmcnt(0)" ::: "memory");
  __builtin_amdgcn_s_barrier();
  asm volatile("" ::: "memory");
}

__device__ __forceinline__ f32x16 mm_tile(const ushort* A, const ushort* B,
                                          int lr, int lh) {
  f32x16 a0, a1;
  #pragma unroll
  for (int i = 0; i < 16; ++i) { a0[i] = 0.f; a1[i] = 0.f; }
  #pragma unroll
  for (int kb = 0; kb < 8; kb += 2) {
    const int o0 = lr * SK + 16 * kb + 8 * lh, o1 = o0 + 16;
    a0 = __builtin_amdgcn_mfma_f32_32x32x16_bf16(*(const s16x8*)(A + o0),
                                                 *(const s16x8*)(B + o0), a0, 0, 0, 0);
    a1 = __builtin_amdgcn_mfma_f32_32x32x16_bf16(*(const s16x8*)(A + o1),
                                                 *(const s16x8*)(B + o1), a1, 0, 0, 0);
  }
  return a0 + a1;
}

__global__ __launch_bounds__(256, 2)
void gdn_chunk_kernel(const float* __restrict__ qg, const float* __restrict__ kg,
                      const float* __restrict__ vg, const float* __restrict__ gg,
                      const float* __restrict__ bg, const float* __restrict__ s0,
                      float* __restrict__ out)
{
  const int bh = blockIdx.x >> 3;         // head 0..63
  const int v0 = (blockIdx.x & 7) * VS;   // V-slice base (16 cols)
  const int t  = threadIdx.x;
  const int w  = t >> 6;                  // wave 0..3
  const int l  = t & 63;
  const int lr = l & 31;
  const int lh = l >> 5;
  const int r8 = t >> 3;                  // q/k staging row 0..31
  const int c8 = t & 7;                   // q/k staging float4 slot 0..7

  __shared__ __align__(16) ushort Kh[C * SK];    // bf16 k-hat [r][k]
  __shared__ __align__(16) ushort Qh[C * SK];    // bf16 scale*q-hat [r][k]
  __shared__ __align__(16) ushort KhT[K_ * SR];  // bf16 k-hat^T [k][r]
  __shared__ __align__(16) ushort SbT[32 * SK];  // bf16 S^T [v][k] (rows 16-31 dup)
  __shared__ __align__(16) ushort UT[32 * SR];   // bf16 U^T [v][r] (rows 16-31 dup)
  __shared__ __align__(16) float Wm[C * SF], Xm[C * SF], Gm[C * SF], Mm[C * SF];
  __shared__ __align__(16) float Vs[C * VS];     // raw v slice [r][v]
  __shared__ float ls_g[C], ls_b[C], ls_eb[C], ls_emb[C];

  // ---- register-resident state: wave w owns k-rows [32w,32w+32), col v0+lr (lr<16 valid) ----
  f32x16 S;
  {
    const float* sp = s0 + ((size_t)bh * K_ + 32 * w) * V_ + v0 + (lr & 15);
    #pragma unroll
    for (int i = 0; i < 16; i += 2) {
      int row = (i & 3) + 8 * (i >> 2) + 4 * lh;
      S[i]     = sp[(size_t)row * V_];
      S[i + 1] = sp[(size_t)(row + 1) * V_];
      unsigned pack = (unsigned)f2bf(S[i]) | ((unsigned)f2bf(S[i + 1]) << 16);
      *(unsigned*)(SbT + lr * SK + 32 * w + row) = pack;
    }
  }

  const float* qh  = qg + (size_t)bh * T_ * K_;
  const float* kh  = kg + (size_t)bh * T_ * K_;
  const float* vh  = vg + (size_t)bh * T_ * V_;
  const float* ghp = gg + (size_t)bh * T_;
  const float* bhp = bg + (size_t)bh * T_;
  float* oh = out + (size_t)bh * T_ * V_;

  // ---- prologue: prefetch chunk 0 into registers ----
  float4 pq[4], pk[4], pv;
  float pg = 0.f;
  {
    const float4* q4 = (const float4*)(qh + (size_t)r8 * K_);
    const float4* k4 = (const float4*)(kh + (size_t)r8 * K_);
    #pragma unroll
    for (int c = 0; c < 4; ++c) { pq[c] = q4[c8 + 8 * c]; pk[c] = k4[c8 + 8 * c]; }
    if (t < 128)
      pv = ((const float4*)(vh + (size_t)(t >> 2) * V_ + v0))[t & 3];
    if (t < C)          pg = ghp[t];
    else if (t < 2 * C) pg = bhp[t - C];
  }

  for (int ch = 0; ch < NCH; ++ch) {
    const int t0 = ch * C;
    bar_lds();   // prev chunk's ph4 LDS reads done before we overwrite staging

    // ================= ph1: normalize + store staged regs =================
    {
      float sq = 0.f, sk = 0.f;
      #pragma unroll
      for (int c = 0; c < 4; ++c) {
        sq += pq[c].x * pq[c].x + pq[c].y * pq[c].y + pq[c].z * pq[c].z + pq[c].w * pq[c].w;
        sk += pk[c].x * pk[c].x + pk[c].y * pk[c].y + pk[c].z * pk[c].z + pk[c].w * pk[c].w;
      }
      sq += __shfl_xor(sq, 1); sq += __shfl_xor(sq, 2); sq += __shfl_xor(sq, 4);
      sk += __shfl_xor(sk, 1); sk += __shfl_xor(sk, 2); sk += __shfl_xor(sk, 4);
      const float niq = SCALE / fmaxf(sqrtf(sq), 1e-12f);
      const float nik = 1.0f / fmaxf(sqrtf(sk), 1e-12f);
      #pragma unroll
      for (int c = 0; c < 4; ++c) {
        const int f4 = c8 + 8 * c;
        ushort k0 = f2bf(pk[c].x * nik), k1 = f2bf(pk[c].y * nik);
        ushort k2 = f2bf(pk[c].z * nik), k3 = f2bf(pk[c].w * nik);
        ushort q0 = f2bf(pq[c].x * niq), q1 = f2bf(pq[c].y * niq);
        ushort q2 = f2bf(pq[c].z * niq), q3 = f2bf(pq[c].w * niq);
        uint2 upk, upq;
        upk.x = (unsigned)k0 | ((unsigned)k1 << 16);
        upk.y = (unsigned)k2 | ((unsigned)k3 << 16);
        upq.x = (unsigned)q0 | ((unsigned)q1 << 16);
        upq.y = (unsigned)q2 | ((unsigned)q3 << 16);
        *(uint2*)(Kh + r8 * SK + f4 * 4) = upk;
        *(uint2*)(Qh + r8 * SK + f4 * 4) = upq;
        KhT[(f4 * 4 + 0) * SR + r8] = k0;
        KhT[(f4 * 4 + 1) * SR + r8] = k1;
        KhT[(f4 * 4 + 2) * SR + r8] = k2;
        KhT[(f4 * 4 + 3) * SR + r8] = k3;
      }
      if (t < 128) *(float4*)(Vs + (t >> 2) * VS + (t & 3) * 4) = pv;
      if (t < C)          ls_g[t]     = pg;
      else if (t < 2 * C) ls_b[t - C] = pg;
    }
    // ---- prefetch next chunk (stays in flight across lgkm-only barriers) ----
    if (ch + 1 < NCH) {
      const int t1 = t0 + C;
      const float4* q4 = (const float4*)(qh + (size_t)(t1 + r8) * K_);
      const float4* k4 = (const float4*)(kh + (size_t)(t1 + r8) * K_);
      #pragma unroll
      for (int c = 0; c < 4; ++c) { pq[c] = q4[c8 + 8 * c]; pk[c] = k4[c8 + 8 * c]; }
      if (t < 128)
        pv = ((const float4*)(vh + (size_t)(t1 + (t >> 2)) * V_ + v0))[t & 3];
      if (t < C)          pg = ghp[t1 + t];
      else if (t < 2 * C) pg = bhp[t1 + t - C];
    }
    bar_lds();

    // ================= ph2: MFMA W/X/G/M + decay prefix =================
    if (w == 3 && l < 32) {   // inclusive prefix of g -> e^{b}, e^{-b}
      float x = ls_g[l];
      #pragma unroll
      for (int d = 1; d < 32; d <<= 1) {
        float y = __shfl_up(x, d);
        if (l >= d) x += y;
      }
      ls_eb[l]  = expf(x);
      ls_emb[l] = expf(-x);
    }
    {
      f32x16 acc;
      float* dst;
      if (w == 0)      { acc = mm_tile(Kh, SbT, lr, lh); dst = Wm; }
      else if (w == 1) { acc = mm_tile(Qh, SbT, lr, lh); dst = Xm; }
      else if (w == 2) { acc = mm_tile(Qh, Kh,  lr, lh); dst = Gm; }
      else             { acc = mm_tile(Kh, Kh,  lr, lh); dst = Mm; }
      #pragma unroll
      for (int i = 0; i < 16; ++i) {
        int row = (i & 3) + 8 * (i >> 2) + 4 * lh;
        float val = acc[i];
        if (w == 2 && lr > row) val = 0.f;   // mask G to j<=r
        dst[row * SF + lr] = val;
      }
    }
    bar_lds();

    // ================= ph3: redundant per-wave solve (u in registers) =====
    float u[32];
    {
      const int col = lr & 15;
      float bv[32];
      #pragma unroll
      for (int r = 0; r < 32; ++r)
        bv[r] = ls_emb[r] * Vs[r * VS + col] - Wm[r * SF + col];
      #pragma unroll
      for (int r = 0; r < 32; ++r) {
        float a = bv[r];
        float p0 = 0.f, p1 = 0.f, p2 = 0.f, p3 = 0.f;
        const float* mr = Mm + r * SF;
        #pragma unroll
        for (int jb = 0; jb + 4 <= r; jb += 4) {
          float4 m4 = *(const float4*)(mr + jb);
          p0 = fmaf(m4.x, u[jb + 0], p0);
          p1 = fmaf(m4.y, u[jb + 1], p1);
          p2 = fmaf(m4.z, u[jb + 2], p2);
          p3 = fmaf(m4.w, u[jb + 3], p3);
        }
        #pragma unroll
        for (int j = (r & ~3); j < r; ++j) p1 = fmaf(mr[j], u[j], p1);
        a -= (p0 + p1) + (p2 + p3);
        u[r] = ls_b[r] * a;
      }
    }
    if (w == 0 && l < 32) {   // one copy of bf16 U^T (rows 16-31 duplicate cols)
      #pragma unroll
      for (int jb = 0; jb < 4; ++jb) {
        s16x8 pkv;
        #pragma unroll
        for (int e = 0; e < 8; ++e) pkv[e] = (short)f2bf(u[8 * jb + e]);
        *(s16x8*)(UT + lr * SR + 8 * jb) = pkv;
      }
    }
    // ---- O rows from register u: o_r = e^{b_r}(X[r] + sum_j G[r][j] u_j) ----
    {
      #pragma unroll
      for (int m = 0; m < 4; ++m) {
        const int r = 8 * w + 4 * lh + m;
        float o0 = Xm[r * SF + lr], o1 = 0.f, o2 = 0.f, o3 = 0.f;
        const float* gr = Gm + r * SF;
        #pragma unroll
        for (int jb = 0; jb < 32; jb += 4) {
          float4 g4 = *(const float4*)(gr + jb);
          o0 = fmaf(g4.x, u[jb + 0], o0);
          o1 = fmaf(g4.y, u[jb + 1], o1);
          o2 = fmaf(g4.z, u[jb + 2], o2);
          o3 = fmaf(g4.w, u[jb + 3], o3);
        }
        if (lr < 16)
          oh[(size_t)(t0 + r) * V_ + v0 + lr] = ls_eb[r] * ((o0 + o1) + (o2 + o3));
      }
    }
    bar_lds();   // UT visible

    // ================= ph4: state update (MFMA) =================
    {
      f32x16 acc = S;
      #pragma unroll
      for (int rb = 0; rb < 2; ++rb) {
        s16x8 a = *(const s16x8*)(KhT + (32 * w + lr) * SR + 16 * rb + 8 * lh);
        s16x8 b = *(const s16x8*)(UT + lr * SR + 16 * rb + 8 * lh);
        acc = __builtin_amdgcn_mfma_f32_32x32x16_bf16(a, b, acc, 0, 0, 0);
      }
      const float ebL = ls_eb[31];
      #pragma unroll
      for (int i = 0; i < 16; i += 2) {
        S[i]     = ebL * acc[i];
        S[i + 1] = ebL * acc[i + 1];
        int row = (i & 3) + 8 * (i >> 2) + 4 * lh;
        unsigned pack = (unsigned)f2bf(S[i]) | ((unsigned)f2bf(S[i + 1]) << 16);
        *(unsigned*)(SbT + lr * SK + 32 * w + row) = pack;
      }
    }
  }

  // ---- final state ----
  if (lr < 16) {
    float* sp = out + (size_t)BHn * T_ * V_
                    + ((size_t)bh * K_ + 32 * w) * V_ + v0 + lr;
    #pragma unroll
    for (int i = 0; i < 16; ++i) {
      int row = (i & 3) + 8 * (i >> 2) + 4 * lh;
      sp[(size_t)row * V_] = S[i];
    }
  }
}

extern "C" void kernel_launch(void* const* d_in, const int* in_sizes, int n_in,
                              void* d_out, int out_size, void* d_ws, size_t ws_size,
                              hipStream_t stream) {
  const float* q    = (const float*)d_in[0];
  const float* k    = (const float*)d_in[1];
  const float* v    = (const float*)d_in[2];
  const float* g    = (const float*)d_in[3];
  const float* beta = (const float*)d_in[4];
  const float* s0   = (const float*)d_in[5];
  float* out = (float*)d_out;
  hipLaunchKernelGGL(gdn_chunk_kernel, dim3(BHn * NS), dim3(256), 0, stream,
                     q, k, v, g, beta, s0, out);
}

// Round 6
// 209.957 us; speedup vs baseline: 2.0440x; 2.0440x over previous
//
#include <hip/hip_runtime.h>
#include <hip/hip_bf16.h>
#include <math.h>

typedef float f32x16 __attribute__((ext_vector_type(16)));
typedef short s16x8 __attribute__((ext_vector_type(8)));
typedef unsigned int u32;

namespace {
constexpr int B_ = 4, H_ = 16, T_ = 2048, K_ = 128, V_ = 128;
constexpr int BHn = B_ * H_;
constexpr int C = 32;            // chunk length
constexpr int NCH = T_ / C;      // 64 chunks
constexpr int NS = 4;            // V slices (seq pass)
constexpr int VS = V_ / NS;      // 32 cols per block
constexpr float SCALE = 0.08838834764831845f; // 128^-0.5
constexpr int SK = 136;          // ush stride, [*][128] arrays
constexpr int SRT = 40;          // ush stride, KhT [128][32]
constexpr int SRU = 40;          // ush stride, UT/Bb [32][32]
constexpr int SG = 48;           // ush stride, T/G tiles [32][32]
constexpr int SF = 36;           // f32 stride, Mm [32][32]
constexpr size_t WSCH = 4608;    // ws bytes per (head,chunk): T 2048 | G 2048 | scal 384 | pad
}

__device__ __forceinline__ ushort f2bf(float x) {
  unsigned u = __builtin_bit_cast(unsigned, x);
  u += 0x7FFF + ((u >> 16) & 1);       // RNE
  return (ushort)(u >> 16);
}
__device__ __forceinline__ int rowmap(int i, int lh) { return (i & 3) + 8 * (i >> 2) + 4 * lh; }

// barrier waiting only on LDS ops: global loads/stores stay in flight
__device__ __forceinline__ void bar_lds() {
  asm volatile("s_waitcnt lgkmcnt(0)" ::: "memory");
  __builtin_amdgcn_s_barrier();
  asm volatile("" ::: "memory");
}

// full-K (128) tile matmul: returns A * Barr^T, both arrays stride SK
__device__ __forceinline__ f32x16 mm8(const ushort* A, const ushort* B, int lr, int lh) {
  f32x16 a0, a1;
  #pragma unroll
  for (int i = 0; i < 16; ++i) { a0[i] = 0.f; a1[i] = 0.f; }
  #pragma unroll
  for (int kb = 0; kb < 8; kb += 2) {
    const int o0 = lr * SK + 16 * kb + 8 * lh, o1 = o0 + 16;
    a0 = __builtin_amdgcn_mfma_f32_32x32x16_bf16(*(const s16x8*)(A + o0),
                                                 *(const s16x8*)(B + o0), a0, 0, 0, 0);
    a1 = __builtin_amdgcn_mfma_f32_32x32x16_bf16(*(const s16x8*)(A + o1),
                                                 *(const s16x8*)(B + o1), a1, 0, 0, 0);
  }
  return a0 + a1;
}
// K=32 tile matmul with C-in: acc += A * Barr^T
__device__ __forceinline__ f32x16 mm2(const ushort* A, int sa, const ushort* B, int sb,
                                      f32x16 acc, int lr, int lh) {
  #pragma unroll
  for (int kb = 0; kb < 2; ++kb) {
    s16x8 a = *(const s16x8*)(A + lr * sa + 16 * kb + 8 * lh);
    s16x8 b = *(const s16x8*)(B + lr * sb + 16 * kb + 8 * lh);
    acc = __builtin_amdgcn_mfma_f32_32x32x16_bf16(a, b, acc, 0, 0, 0);
  }
  return acc;
}

// ============ pass 1: chunk-local precompute (4096 independent blocks) ============
__global__ __launch_bounds__(256, 2)
void gdn_pre_kernel(const float* __restrict__ qg, const float* __restrict__ kg,
                    const float* __restrict__ gg, const float* __restrict__ bg,
                    char* __restrict__ ws)
{
  const int bid = blockIdx.x;
  const int bh = bid >> 6, ch = bid & 63;
  const int t = threadIdx.x, w = t >> 6, l = t & 63, lr = l & 31, lh = l >> 5;
  const int r8 = t >> 3, c8 = t & 7;
  const int t0 = ch * C;

  __shared__ __align__(16) ushort Kh[C * SK], Qh[C * SK];
  __shared__ __align__(16) float Mm[C * SF];
  __shared__ __align__(16) ushort Tt[C * 32], Gt[C * 32];
  __shared__ float ls_g[C], ls_b[C], ls_eb[C], ls_emb[C];

  { // stage + normalize q,k
    const float4* q4 = (const float4*)(qg + ((size_t)bh * T_ + t0 + r8) * K_);
    const float4* k4 = (const float4*)(kg + ((size_t)bh * T_ + t0 + r8) * K_);
    float4 qv[4], kv[4]; float sq = 0.f, sk = 0.f;
    #pragma unroll
    for (int c = 0; c < 4; ++c) {
      qv[c] = q4[c8 + 8 * c]; kv[c] = k4[c8 + 8 * c];
      sq += qv[c].x*qv[c].x + qv[c].y*qv[c].y + qv[c].z*qv[c].z + qv[c].w*qv[c].w;
      sk += kv[c].x*kv[c].x + kv[c].y*kv[c].y + kv[c].z*kv[c].z + kv[c].w*kv[c].w;
    }
    sq += __shfl_xor(sq, 1); sq += __shfl_xor(sq, 2); sq += __shfl_xor(sq, 4);
    sk += __shfl_xor(sk, 1); sk += __shfl_xor(sk, 2); sk += __shfl_xor(sk, 4);
    const float niq = SCALE / fmaxf(sqrtf(sq), 1e-12f);
    const float nik = 1.0f / fmaxf(sqrtf(sk), 1e-12f);
    #pragma unroll
    for (int c = 0; c < 4; ++c) {
      const int f4 = c8 + 8 * c;
      uint2 upk, upq;
      upk.x = (u32)f2bf(kv[c].x*nik) | ((u32)f2bf(kv[c].y*nik) << 16);
      upk.y = (u32)f2bf(kv[c].z*nik) | ((u32)f2bf(kv[c].w*nik) << 16);
      upq.x = (u32)f2bf(qv[c].x*niq) | ((u32)f2bf(qv[c].y*niq) << 16);
      upq.y = (u32)f2bf(qv[c].z*niq) | ((u32)f2bf(qv[c].w*niq) << 16);
      *(uint2*)(Kh + r8 * SK + f4 * 4) = upk;
      *(uint2*)(Qh + r8 * SK + f4 * 4) = upq;
    }
    if (t < C)          ls_g[t]     = gg[(size_t)bh * T_ + t0 + t];
    else if (t < 2 * C) ls_b[t - C] = bg[(size_t)bh * T_ + t0 + t - C];
  }
  __syncthreads();
  if (w == 3 && l < 32) {   // inclusive prefix of g
    float x = ls_g[l];
    #pragma unroll
    for (int d = 1; d < 32; d <<= 1) { float y = __shfl_up(x, d); if (l >= d) x += y; }
    ls_eb[l] = expf(x); ls_emb[l] = expf(-x);
  }
  if (w == 0) {
    f32x16 acc = mm8(Kh, Kh, lr, lh);
    #pragma unroll
    for (int i = 0; i < 16; ++i) Mm[rowmap(i, lh) * SF + lr] = acc[i];
  }
  if (w == 1) {
    f32x16 acc = mm8(Qh, Kh, lr, lh);
    #pragma unroll
    for (int i = 0; i < 16; ++i) {
      int row = rowmap(i, lh);
      Gt[row * 32 + lr] = (lr <= row) ? f2bf(acc[i]) : (ushort)0;
    }
  }
  __syncthreads();
  if (w == 2 && l < 32) {   // T = (I + tril_strict(diag(b) M))^-1, column l
    const int j = l;
    float x[32];
    #pragma unroll
    for (int m = 0; m < 32; ++m) x[m] = (m == j) ? 1.f : 0.f;
    #pragma unroll
    for (int r = 1; r < 32; ++r) {
      const float* mr = Mm + r * SF;
      float p0 = 0.f, p1 = 0.f, p2 = 0.f, p3 = 0.f;
      #pragma unroll
      for (int jb = 0; jb + 4 <= r; jb += 4) {
        float4 m4 = *(const float4*)(mr + jb);
        p0 = fmaf(m4.x, x[jb + 0], p0);
        p1 = fmaf(m4.y, x[jb + 1], p1);
        p2 = fmaf(m4.z, x[jb + 2], p2);
        p3 = fmaf(m4.w, x[jb + 3], p3);
      }
      #pragma unroll
      for (int m = (r & ~3); m < r; ++m) p1 = fmaf(mr[m], x[m], p1);
      float xr = -ls_b[r] * ((p0 + p1) + (p2 + p3));
      if (r > j) x[r] = xr;
    }
    #pragma unroll
    for (int r = 0; r < 32; ++r) Tt[r * 32 + j] = f2bf(x[r]);
  }
  __syncthreads();
  { // copy to ws
    char* wsb = ws + ((size_t)bh * NCH + ch) * WSCH;
    u32* wT = (u32*)wsb; u32* wG = (u32*)(wsb + 2048); float* wS = (float*)(wsb + 4096);
    const u32* sT = (const u32*)Tt; const u32* sG = (const u32*)Gt;
    wT[t] = sT[t]; wT[t + 256] = sT[t + 256];
    wG[t] = sG[t]; wG[t + 256] = sG[t + 256];
    if (t < 32)      wS[t] = ls_eb[t];
    else if (t < 64) wS[t] = ls_b[t - 32] * ls_emb[t - 32];   // bev
    else if (t < 96) wS[t] = ls_b[t - 64];                    // bet
  }
}

// ============ pass 2: sequential scan over chunks (256 blocks) ============
__global__ __launch_bounds__(256, 1)
void gdn_seq_kernel(const float* __restrict__ qg, const float* __restrict__ kg,
                    const float* __restrict__ vg, const float* __restrict__ s0,
                    const char* __restrict__ ws, float* __restrict__ out)
{
  const int bid = blockIdx.x;
  // co-locate the 4 V-slices of a head on one XCD (shared q/k/ws L2 reuse)
  const int xcd = bid & 7, qd = bid >> 3;
  const int bh = (qd >> 2) * 8 + xcd;
  const int v0 = (qd & 3) * VS;
  const int t = threadIdx.x, w = t >> 6, l = t & 63, lr = l & 31, lh = l >> 5;
  const int r8 = t >> 3, c8 = t & 7;

  __shared__ __align__(16) ushort Kh[2][C * SK], Qh[2][C * SK], KhT[2][K_ * SRT];
  __shared__ __align__(16) ushort Tl[2][C * SG], Gl[2][C * SG];
  __shared__ __align__(16) float  vl[2][C * VS];
  __shared__ float ls_eb[2][C], ls_bev[2][C], ls_bet[2][C];
  __shared__ __align__(16) ushort SbT[32 * SK], UT[32 * SRU], Bb[32 * SRU];

  // register-resident state: wave w owns k-rows [32w,32w+32), col v0+lr
  f32x16 S;
  {
    const float* sp = s0 + ((size_t)bh * K_ + 32 * w) * V_ + v0 + lr;
    #pragma unroll
    for (int i = 0; i < 16; i += 2) {
      int row = rowmap(i, lh);
      S[i]     = sp[(size_t)row * V_];
      S[i + 1] = sp[(size_t)(row + 1) * V_];
      *(u32*)(SbT + lr * SK + 32 * w + row) =
          (u32)f2bf(S[i]) | ((u32)f2bf(S[i + 1]) << 16);
    }
  }

  const float* qh = qg + (size_t)bh * T_ * K_;
  const float* kh = kg + (size_t)bh * T_ * K_;
  const float* vh = vg + (size_t)bh * T_ * V_;
  const char* wsh = ws + (size_t)bh * NCH * WSCH;
  float* oh = out + (size_t)bh * T_ * V_;

  float4 pq[4], pk[4], pv;
  u32 pT0, pT1, pG0, pG1; float psc = 0.f;

  auto prefetch = [&](int cc) {
    const float4* q4 = (const float4*)(qh + (size_t)(cc * C + r8) * K_);
    const float4* k4 = (const float4*)(kh + (size_t)(cc * C + r8) * K_);
    #pragma unroll
    for (int c = 0; c < 4; ++c) { pq[c] = q4[c8 + 8 * c]; pk[c] = k4[c8 + 8 * c]; }
    pv = *(const float4*)(vh + (size_t)(cc * C + r8) * V_ + v0 + 4 * c8);
    const char* wsb = wsh + (size_t)cc * WSCH;
    pT0 = ((const u32*)wsb)[t];          pT1 = ((const u32*)wsb)[t + 256];
    pG0 = ((const u32*)(wsb + 2048))[t]; pG1 = ((const u32*)(wsb + 2048))[t + 256];
    if (t < 96) psc = ((const float*)(wsb + 4096))[t];
  };
  auto stage = [&](int b) {
    float sq = 0.f, sk = 0.f;
    #pragma unroll
    for (int c = 0; c < 4; ++c) {
      sq += pq[c].x*pq[c].x + pq[c].y*pq[c].y + pq[c].z*pq[c].z + pq[c].w*pq[c].w;
      sk += pk[c].x*pk[c].x + pk[c].y*pk[c].y + pk[c].z*pk[c].z + pk[c].w*pk[c].w;
    }
    sq += __shfl_xor(sq, 1); sq += __shfl_xor(sq, 2); sq += __shfl_xor(sq, 4);
    sk += __shfl_xor(sk, 1); sk += __shfl_xor(sk, 2); sk += __shfl_xor(sk, 4);
    const float niq = SCALE / fmaxf(sqrtf(sq), 1e-12f);
    const float nik = 1.0f / fmaxf(sqrtf(sk), 1e-12f);
    #pragma unroll
    for (int c = 0; c < 4; ++c) {
      const int f4 = c8 + 8 * c;
      ushort k0 = f2bf(pk[c].x*nik), k1 = f2bf(pk[c].y*nik);
      ushort k2 = f2bf(pk[c].z*nik), k3 = f2bf(pk[c].w*nik);
      uint2 upk, upq;
      upk.x = (u32)k0 | ((u32)k1 << 16);
      upk.y = (u32)k2 | ((u32)k3 << 16);
      upq.x = (u32)f2bf(pq[c].x*niq) | ((u32)f2bf(pq[c].y*niq) << 16);
      upq.y = (u32)f2bf(pq[c].z*niq) | ((u32)f2bf(pq[c].w*niq) << 16);
      *(uint2*)(&Kh[b][0] + r8 * SK + f4 * 4) = upk;
      *(uint2*)(&Qh[b][0] + r8 * SK + f4 * 4) = upq;
      KhT[b][(f4 * 4 + 0) * SRT + r8] = k0;
      KhT[b][(f4 * 4 + 1) * SRT + r8] = k1;
      KhT[b][(f4 * 4 + 2) * SRT + r8] = k2;
      KhT[b][(f4 * 4 + 3) * SRT + r8] = k3;
    }
    *(float4*)(&vl[b][0] + r8 * VS + 4 * c8) = pv;
    { int e = t;       *(u32*)(&Tl[b][0] + (e >> 4) * SG + 2 * (e & 15)) = pT0; }
    { int e = t + 256; *(u32*)(&Tl[b][0] + (e >> 4) * SG + 2 * (e & 15)) = pT1; }
    { int e = t;       *(u32*)(&Gl[b][0] + (e >> 4) * SG + 2 * (e & 15)) = pG0; }
    { int e = t + 256; *(u32*)(&Gl[b][0] + (e >> 4) * SG + 2 * (e & 15)) = pG1; }
    if (t < 32)      ls_eb[b][t]       = psc;
    else if (t < 64) ls_bev[b][t - 32] = psc;
    else if (t < 96) ls_bet[b][t - 64] = psc;
  };

  prefetch(0); stage(0); prefetch(1);
  bar_lds();

  f32x16 Xacc;
  for (int ch = 0; ch < NCH; ++ch) {
    const int cur = ch & 1, t0 = ch * C;
    // ---------- phase A ----------
    f32x16 Wacc;
    if (w == 0) Wacc = mm8(&Kh[cur][0], SbT, lr, lh);
    if (w == 1) Xacc = mm8(&Qh[cur][0], SbT, lr, lh);
    if (ch + 1 < NCH) stage(cur ^ 1);
    if (ch + 2 < NCH) prefetch(ch + 2);
    if (w == 0) {
      #pragma unroll
      for (int p = 0; p < 8; ++p) {
        const int i0 = 2 * p, row = rowmap(i0, lh);
        float b0 = ls_bev[cur][row]     * vl[cur][row * VS + lr]       - ls_bet[cur][row]     * Wacc[i0];
        float b1 = ls_bev[cur][row + 1] * vl[cur][(row + 1) * VS + lr] - ls_bet[cur][row + 1] * Wacc[i0 + 1];
        *(u32*)(Bb + lr * SRU + row) = (u32)f2bf(b0) | ((u32)f2bf(b1) << 16);
      }
      f32x16 Uacc;
      #pragma unroll
      for (int i = 0; i < 16; ++i) Uacc[i] = 0.f;
      Uacc = mm2(&Tl[cur][0], SG, Bb, SRU, Uacc, lr, lh);
      #pragma unroll
      for (int p = 0; p < 8; ++p) {
        const int i0 = 2 * p, row = rowmap(i0, lh);
        *(u32*)(UT + lr * SRU + row) = (u32)f2bf(Uacc[i0]) | ((u32)f2bf(Uacc[i0 + 1]) << 16);
      }
    }
    bar_lds();
    // ---------- phase C ----------
    if (w == 1) {
      f32x16 Oacc = mm2(&Gl[cur][0], SG, UT, SRU, Xacc, lr, lh);
      #pragma unroll
      for (int i = 0; i < 16; ++i) {
        int row = rowmap(i, lh);
        oh[(size_t)(t0 + row) * V_ + v0 + lr] = ls_eb[cur][row] * Oacc[i];
      }
    }
    {
      f32x16 acc = mm2(&KhT[cur][0] + 32 * w * SRT, SRT, UT, SRU, S, lr, lh);
      const float ebL = ls_eb[cur][31];
      #pragma unroll
      for (int i = 0; i < 16; i += 2) {
        S[i]     = ebL * acc[i];
        S[i + 1] = ebL * acc[i + 1];
        int row = rowmap(i, lh);
        *(u32*)(SbT + lr * SK + 32 * w + row) =
            (u32)f2bf(S[i]) | ((u32)f2bf(S[i + 1]) << 16);
      }
    }
    bar_lds();
  }

  { // final state
    float* sp = out + (size_t)BHn * T_ * V_ + ((size_t)bh * K_ + 32 * w) * V_ + v0 + lr;
    #pragma unroll
    for (int i = 0; i < 16; ++i) sp[(size_t)rowmap(i, lh) * V_] = S[i];
  }
}

extern "C" void kernel_launch(void* const* d_in, const int* in_sizes, int n_in,
                              void* d_out, int out_size, void* d_ws, size_t ws_size,
                              hipStream_t stream) {
  const float* q    = (const float*)d_in[0];
  const float* k    = (const float*)d_in[1];
  const float* v    = (const float*)d_in[2];
  const float* g    = (const float*)d_in[3];
  const float* beta = (const float*)d_in[4];
  const float* s0   = (const float*)d_in[5];
  float* out = (float*)d_out;
  char* ws = (char*)d_ws;   // needs 64*64*4608 = 18.9 MB
  hipLaunchKernelGGL(gdn_pre_kernel, dim3(BHn * NCH), dim3(256), 0, stream,
                     q, k, g, beta, ws);
  hipLaunchKernelGGL(gdn_seq_kernel, dim3(BHn * NS), dim3(256), 0, stream,
                     q, k, v, s0, ws, out);
}